// Round 1
// baseline (103.664 us; speedup 1.0000x reference)
//
#include <hip/hip_runtime.h>
#include <hip/hip_bf16.h>

typedef unsigned short u16;
typedef __attribute__((ext_vector_type(8))) short short8;
typedef __attribute__((ext_vector_type(4))) float f32x4;

#define NROWS 4096
#define DIM   512
#define TINV  10.0f   // 1/temperature

// round-to-nearest-even f32 -> bf16 bits
__device__ __forceinline__ u16 f2bf(float x) {
    unsigned u = __float_as_uint(x);
    unsigned r = (u + 0x7FFFu + ((u >> 16) & 1u)) >> 16;
    return (u16)r;
}

// ---------------------------------------------------------------------------
// Kernel 1: L2-normalize rows, emit bf16. One 64-lane wave per row.
// grid = 1024 blocks x 256 threads (4 rows/block)
// ---------------------------------------------------------------------------
__global__ __launch_bounds__(256) void k_norm(const float* __restrict__ in,
                                              u16* __restrict__ out) {
    const int row  = blockIdx.x * 4 + (threadIdx.x >> 6);
    const int lane = threadIdx.x & 63;
    const float* rp = in + (size_t)row * DIM;

    float4 v0 = ((const float4*)rp)[lane];        // elems 4*lane   .. +3
    float4 v1 = ((const float4*)rp)[lane + 64];   // elems 256+4*lane .. +3

    float ssq = v0.x*v0.x + v0.y*v0.y + v0.z*v0.z + v0.w*v0.w
              + v1.x*v1.x + v1.y*v1.y + v1.z*v1.z + v1.w*v1.w;
    #pragma unroll
    for (int m = 32; m; m >>= 1) ssq += __shfl_xor(ssq, m);

    const float scale = 1.0f / fmaxf(sqrtf(ssq), 1e-12f);

    u16* op = out + (size_t)row * DIM;
    u16 o0[4], o1[4];
    o0[0] = f2bf(v0.x * scale); o0[1] = f2bf(v0.y * scale);
    o0[2] = f2bf(v0.z * scale); o0[3] = f2bf(v0.w * scale);
    o1[0] = f2bf(v1.x * scale); o1[1] = f2bf(v1.y * scale);
    o1[2] = f2bf(v1.z * scale); o1[3] = f2bf(v1.w * scale);
    ((ushort4*)op)[lane]      = make_ushort4(o0[0], o0[1], o0[2], o0[3]);
    ((ushort4*)op)[lane + 64] = make_ushort4(o1[0], o1[1], o1[2], o1[3]);
}

// ---------------------------------------------------------------------------
// Kernel 2: sim = f f^T in 128x128 tiles; fused epilogue:
//   S[i] += sum_{j in tile, j!=i} exp((s_ij - 1) * 10)   (atomicAdd)
//   P[i]  = s_ij where j == i^2048                        (one writer/row)
// m97 structure: BK=32, global_load_lds(16B), 4 waves in 2x2, 16x16x32 MFMA.
// ---------------------------------------------------------------------------
__device__ __forceinline__ void gload_lds16(const u16* g, u16* l) {
    __builtin_amdgcn_global_load_lds(
        (const __attribute__((address_space(1))) void*)g,
        (__attribute__((address_space(3))) void*)l, 16, 0, 0);
}

__global__ __launch_bounds__(256) void k_gemm(const u16* __restrict__ fb,
                                              float* __restrict__ S,
                                              float* __restrict__ P) {
    __shared__ u16 lA[128 * 32];
    __shared__ u16 lB[128 * 32];

    const int tid  = threadIdx.x;
    const int lane = tid & 63;
    const int wid  = tid >> 6;
    const int wr   = wid >> 1;     // wave row   (0..1) -> 64-row slab
    const int wc   = wid & 1;      // wave col   (0..1) -> 64-col slab
    const int brow = blockIdx.y * 128;
    const int bcol = blockIdx.x * 128;

    const int lr = lane & 15;      // fragment row/col within 16
    const int kg = lane >> 4;      // k-group (0..3), 8 elems each

    f32x4 acc[4][4];
    #pragma unroll
    for (int m = 0; m < 4; ++m)
        #pragma unroll
        for (int n = 0; n < 4; ++n)
            acc[m][n] = (f32x4){0.f, 0.f, 0.f, 0.f};

    for (int kk = 0; kk < DIM; kk += 32) {
        // ---- stage A,B tiles (128x32 bf16 = 8 KB each) ----
        #pragma unroll
        for (int i = 0; i < 2; ++i) {
            const int c = tid + i * 256;     // 16B chunk id, 0..511
            const int r = c >> 2;            // tile row
            const int o = (c & 3) * 8;       // elem offset in row
            gload_lds16(fb + (size_t)(brow + r) * DIM + kk + o, lA + c * 8);
            gload_lds16(fb + (size_t)(bcol + r) * DIM + kk + o, lB + c * 8);
        }
        __syncthreads();   // compiler emits vmcnt(0) drain before barrier

        short8 a[4], b[4];
        #pragma unroll
        for (int m = 0; m < 4; ++m)
            a[m] = *(const short8*)&lA[(wr * 64 + m * 16 + lr) * 32 + kg * 8];
        #pragma unroll
        for (int n = 0; n < 4; ++n)
            b[n] = *(const short8*)&lB[(wc * 64 + n * 16 + lr) * 32 + kg * 8];

        #pragma unroll
        for (int m = 0; m < 4; ++m)
            #pragma unroll
            for (int n = 0; n < 4; ++n)
                acc[m][n] = __builtin_amdgcn_mfma_f32_16x16x32_bf16(
                    a[m], b[n], acc[m][n], 0, 0, 0);
        __syncthreads();   // before overwriting LDS next iter
    }

    // ---- epilogue: exp, mask diag, extract positive, row-sum, atomic ----
    // C/D layout: col = lane&15, row = (lane>>4)*4 + reg   [m89]
    #pragma unroll
    for (int m = 0; m < 4; ++m) {
        #pragma unroll
        for (int r = 0; r < 4; ++r) {
            const int grow = brow + wr * 64 + m * 16 + kg * 4 + r;
            float rs = 0.f;
            #pragma unroll
            for (int n = 0; n < 4; ++n) {
                const int gcol = bcol + wc * 64 + n * 16 + lr;
                const float s = acc[m][n][r];
                if (gcol == (grow ^ 2048)) P[grow] = s;
                const float e = (gcol == grow) ? 0.f : __expf(TINV * (s - 1.0f));
                rs += e;
            }
            rs += __shfl_xor(rs, 1);
            rs += __shfl_xor(rs, 2);
            rs += __shfl_xor(rs, 4);
            rs += __shfl_xor(rs, 8);
            if (lr == 0) atomicAdd(&S[grow], rs);
        }
    }
}

// ---------------------------------------------------------------------------
// Kernel 3: loss = mean_i (1/T + log S_i - P_i/T)
// ---------------------------------------------------------------------------
__global__ __launch_bounds__(256) void k_final(const float* __restrict__ S,
                                               const float* __restrict__ P,
                                               float* __restrict__ out) {
    __shared__ float red[256];
    float local = 0.f;
    for (int r = threadIdx.x; r < NROWS; r += 256)
        local += TINV + logf(S[r]) - TINV * P[r];
    red[threadIdx.x] = local;
    __syncthreads();
    #pragma unroll
    for (int s = 128; s; s >>= 1) {
        if (threadIdx.x < s) red[threadIdx.x] += red[threadIdx.x + s];
        __syncthreads();
    }
    if (threadIdx.x == 0) out[0] = red[0] * (1.0f / NROWS);
}

// ---------------------------------------------------------------------------
extern "C" void kernel_launch(void* const* d_in, const int* in_sizes, int n_in,
                              void* d_out, int out_size, void* d_ws, size_t ws_size,
                              hipStream_t stream) {
    const float* feat = (const float*)d_in[0];

    u16*   fb = (u16*)d_ws;                                    // 4096*512*2 = 4 MB
    float* S  = (float*)((char*)d_ws + (size_t)NROWS * DIM * 2); // 16 KB
    float* P  = S + NROWS;                                       // 16 KB

    hipMemsetAsync(S, 0, NROWS * sizeof(float), stream);
    k_norm<<<NROWS / 4, 256, 0, stream>>>(feat, fb);
    k_gemm<<<dim3(32, 32), 256, 0, stream>>>(fb, S, P);
    k_final<<<1, 256, 0, stream>>>(S, P, (float*)d_out);
}

// Round 3
// 88.947 us; speedup vs baseline: 1.1655x; 1.1655x over previous
//
#include <hip/hip_runtime.h>
#include <hip/hip_bf16.h>

typedef unsigned short u16;
typedef __attribute__((ext_vector_type(8))) short short8;
typedef __attribute__((ext_vector_type(4))) float f32x4;

#define NROWS 4096
#define DIM   512
#define TINV  10.0f   // 1/temperature

// round-to-nearest-even f32 -> bf16 bits
__device__ __forceinline__ u16 f2bf(float x) {
    unsigned u = __float_as_uint(x);
    unsigned r = (u + 0x7FFFu + ((u >> 16) & 1u)) >> 16;
    return (u16)r;
}

// ---------------------------------------------------------------------------
// Kernel 1: L2-normalize rows -> bf16; also zero the S accumulator.
// grid = 1024 x 256 (4 rows/block, 1 wave/row)
// ---------------------------------------------------------------------------
__global__ __launch_bounds__(256) void k_norm(const float* __restrict__ in,
                                              u16* __restrict__ out,
                                              float* __restrict__ S) {
    const int row  = blockIdx.x * 4 + (threadIdx.x >> 6);
    const int lane = threadIdx.x & 63;
    if (threadIdx.x < 4) S[blockIdx.x * 4 + threadIdx.x] = 0.f;

    const float* rp = in + (size_t)row * DIM;
    float4 v0 = ((const float4*)rp)[lane];
    float4 v1 = ((const float4*)rp)[lane + 64];

    float ssq = v0.x*v0.x + v0.y*v0.y + v0.z*v0.z + v0.w*v0.w
              + v1.x*v1.x + v1.y*v1.y + v1.z*v1.z + v1.w*v1.w;
    #pragma unroll
    for (int m = 32; m; m >>= 1) ssq += __shfl_xor(ssq, m);

    const float scale = 1.0f / fmaxf(sqrtf(ssq), 1e-12f);

    u16* op = out + (size_t)row * DIM;
    ((ushort4*)op)[lane] = make_ushort4(
        f2bf(v0.x * scale), f2bf(v0.y * scale),
        f2bf(v0.z * scale), f2bf(v0.w * scale));
    ((ushort4*)op)[lane + 64] = make_ushort4(
        f2bf(v1.x * scale), f2bf(v1.y * scale),
        f2bf(v1.z * scale), f2bf(v1.w * scale));
}

// ---------------------------------------------------------------------------
// Kernel 2: upper-triangular tiles of sim = f f^T (528 of 1024 tiles).
//  - diag tile  (br==bc): row-sums only (mask diagonal), B aliases A in LDS
//  - off-diag   (br< bc): row-sums -> S[grow], col-sums -> S[gcol]
//  - positive pairs live in tiles bc == br^16: write P[grow] and P[gcol]
// BK=64, XOR-swizzled LDS (chunk ^= row&7), pre-swizzled global source,
// linear global_load_lds dest, swizzled ds_read_b128.
// ---------------------------------------------------------------------------
__device__ __forceinline__ void gload_lds16(const u16* g, u16* l) {
    __builtin_amdgcn_global_load_lds(
        (const __attribute__((address_space(1))) void*)g,
        (__attribute__((address_space(3))) void*)l, 16, 0, 0);
}

__global__ __launch_bounds__(256) void k_gemm(const u16* __restrict__ fb,
                                              float* __restrict__ S,
                                              float* __restrict__ P) {
    const int br = blockIdx.y, bc = blockIdx.x;
    if (bc < br) return;                       // lower triangle: symmetric, skip
    const bool diag = (br == bc);
    const bool posT = (bc == (br ^ 16));       // tile holding positive pairs

    __shared__ u16 lA[128 * 64];
    __shared__ u16 lB[128 * 64];

    const int tid  = threadIdx.x;
    const int lane = tid & 63;
    const int wid  = tid >> 6;
    const int wr   = wid >> 1;
    const int wc   = wid & 1;
    const int brow = br * 128;
    const int bcol = bc * 128;
    const int lr   = lane & 15;
    const int kg   = lane >> 4;

    f32x4 acc[4][4];
    #pragma unroll
    for (int m = 0; m < 4; ++m)
        #pragma unroll
        for (int n = 0; n < 4; ++n)
            acc[m][n] = (f32x4){0.f, 0.f, 0.f, 0.f};

    const u16* Bsrc = diag ? lA : lB;

    for (int kk = 0; kk < DIM; kk += 64) {
        // ---- stage: 128 rows x 64 elems (128B/row, 8 chunks of 16B) ----
        #pragma unroll
        for (int i = 0; i < 4; ++i) {
            const int q  = tid + i * 256;        // chunk id 0..1023
            const int r  = q >> 3;               // tile row
            const int c  = q & 7;                // dest chunk col
            const int sc = c ^ (r & 7);          // swizzled source chunk
            gload_lds16(fb + (size_t)(brow + r) * DIM + kk + sc * 8, lA + q * 8);
        }
        if (!diag) {
            #pragma unroll
            for (int i = 0; i < 4; ++i) {
                const int q  = tid + i * 256;
                const int r  = q >> 3;
                const int c  = q & 7;
                const int sc = c ^ (r & 7);
                gload_lds16(fb + (size_t)(bcol + r) * DIM + kk + sc * 8, lB + q * 8);
            }
        }
        __syncthreads();

        short8 a[4][2], b[4][2];
        #pragma unroll
        for (int m = 0; m < 4; ++m) {
            const int row = wr * 64 + m * 16 + lr;
            #pragma unroll
            for (int ks = 0; ks < 2; ++ks)
                a[m][ks] = *(const short8*)
                    &lA[row * 64 + (((ks * 4 + kg) ^ (row & 7)) * 8)];
        }
        #pragma unroll
        for (int n = 0; n < 4; ++n) {
            const int row = wc * 64 + n * 16 + lr;
            #pragma unroll
            for (int ks = 0; ks < 2; ++ks)
                b[n][ks] = *(const short8*)
                    &Bsrc[row * 64 + (((ks * 4 + kg) ^ (row & 7)) * 8)];
        }

        #pragma unroll
        for (int ks = 0; ks < 2; ++ks)
            #pragma unroll
            for (int m = 0; m < 4; ++m)
                #pragma unroll
                for (int n = 0; n < 4; ++n)
                    acc[m][n] = __builtin_amdgcn_mfma_f32_16x16x32_bf16(
                        a[m][ks], b[n][ks], acc[m][n], 0, 0, 0);
        __syncthreads();
    }

    // ---- epilogue ----
    // C/D layout: col = lane&15, row = (lane>>4)*4 + reg   [m89]
    float cs[4] = {0.f, 0.f, 0.f, 0.f};   // per-(n,lr) column partial sums
    #pragma unroll
    for (int m = 0; m < 4; ++m) {
        #pragma unroll
        for (int r = 0; r < 4; ++r) {
            const int grow = brow + wr * 64 + m * 16 + kg * 4 + r;
            float rs = 0.f;
            #pragma unroll
            for (int n = 0; n < 4; ++n) {
                const int gcol = bcol + wc * 64 + n * 16 + lr;
                const float s = acc[m][n][r];
                if (posT && gcol == (grow ^ 2048)) { P[grow] = s; P[gcol] = s; }
                float e = __expf(TINV * (s - 1.0f));
                if (diag && gcol == grow) e = 0.f;
                rs += e;
                if (!diag) cs[n] += e;
            }
            rs += __shfl_xor(rs, 1);
            rs += __shfl_xor(rs, 2);
            rs += __shfl_xor(rs, 4);
            rs += __shfl_xor(rs, 8);
            if (lr == 0) atomicAdd(&S[grow], rs);
        }
    }
    if (!diag) {
        #pragma unroll
        for (int n = 0; n < 4; ++n) {
            cs[n] += __shfl_xor(cs[n], 16);
            cs[n] += __shfl_xor(cs[n], 32);
            if (kg == 0)
                atomicAdd(&S[bcol + wc * 64 + n * 16 + lr], cs[n]);
        }
    }
}

// ---------------------------------------------------------------------------
// Kernel 3: loss = mean_i (1/T + log S_i - P_i/T)
// ---------------------------------------------------------------------------
__global__ __launch_bounds__(1024) void k_final(const float* __restrict__ S,
                                                const float* __restrict__ P,
                                                float* __restrict__ out) {
    __shared__ float red[1024];
    float local = 0.f;
    #pragma unroll
    for (int i = 0; i < 4; ++i) {
        const int r = threadIdx.x + i * 1024;
        local += TINV + logf(S[r]) - TINV * P[r];
    }
    red[threadIdx.x] = local;
    __syncthreads();
    #pragma unroll
    for (int s = 512; s; s >>= 1) {
        if (threadIdx.x < s) red[threadIdx.x] += red[threadIdx.x + s];
        __syncthreads();
    }
    if (threadIdx.x == 0) out[0] = red[0] * (1.0f / NROWS);
}

// ---------------------------------------------------------------------------
extern "C" void kernel_launch(void* const* d_in, const int* in_sizes, int n_in,
                              void* d_out, int out_size, void* d_ws, size_t ws_size,
                              hipStream_t stream) {
    const float* feat = (const float*)d_in[0];

    u16*   fb = (u16*)d_ws;                                      // 4 MB
    float* S  = (float*)((char*)d_ws + (size_t)NROWS * DIM * 2); // 16 KB
    float* P  = S + NROWS;                                       // 16 KB

    k_norm<<<NROWS / 4, 256, 0, stream>>>(feat, fb, S);
    k_gemm<<<dim3(32, 32), 256, 0, stream>>>(fb, S, P);
    k_final<<<1, 1024, 0, stream>>>(S, P, (float*)d_out);
}